// Round 9
// baseline (274.994 us; speedup 1.0000x reference)
//
#include <hip/hip_runtime.h>
#include <hip/hip_bf16.h>

#define B_ 2
#define N_ 2048
#define E_ 1024
#define H_ 16
#define D_ 64
#define BH_ (B_ * H_)

typedef __attribute__((ext_vector_type(4))) float f32x4;
typedef __attribute__((ext_vector_type(8))) short bf16x8;
typedef __attribute__((ext_vector_type(4))) short s16x4;
typedef __attribute__((ext_vector_type(4))) int i32x4;
typedef __attribute__((ext_vector_type(2))) int i32x2;

#define MFMA(a, b, c) __builtin_amdgcn_mfma_f32_16x16x32_bf16(a, b, c, 0, 0, 0)

#define AS1(p) ((const __attribute__((address_space(1))) unsigned int*)(p))
#define AS3(p) ((__attribute__((address_space(3))) unsigned int*)(p))

static __device__ __forceinline__ unsigned short f2bf(float f) {
    unsigned int u = __builtin_bit_cast(unsigned int, f);
    u += 0x7fff + ((u >> 16) & 1);   // RNE; inputs are finite
    return (unsigned short)(u >> 16);
}
// packed pair -> one dword (v_cvt_pk_bf16_f32 on gfx950)
static __device__ __forceinline__ int pack2bf(float lo, float hi) {
    __hip_bfloat162 t = __float22bfloat162_rn(float2{lo, hi});
    int r;
    __builtin_memcpy(&r, &t, 4);
    return r;
}
static __device__ __forceinline__ bf16x8 cvt8s(const float* __restrict__ p, float sc) {
    f32x4 a = *(const f32x4*)p;
    f32x4 b = *(const f32x4*)(p + 4);
    i32x4 r = {pack2bf(a.x * sc, a.y * sc), pack2bf(a.z * sc, a.w * sc),
               pack2bf(b.x * sc, b.y * sc), pack2bf(b.z * sc, b.w * sc)};
    return __builtin_bit_cast(bf16x8, r);
}

// ---------------------------------------------------------------------------
// Fused projections: z=0 -> qh = (q@Wq^T)*log2e/32, masked rows zeroed,
// layout [bh][n][d]; z=1 -> kh [bh][n][d]; z=2 -> vt [bh][d][n].
// grid (N/64, BH, 3), block 256.
// ---------------------------------------------------------------------------
__global__ __launch_bounds__(256, 4)
void proj_kernel(const float* __restrict__ q, const float* __restrict__ k,
                 const float* __restrict__ v,
                 const float* __restrict__ Wq, const float* __restrict__ Wk,
                 const float* __restrict__ Wv,
                 const int* __restrict__ mask,
                 unsigned short* __restrict__ qh, unsigned short* __restrict__ kh,
                 unsigned short* __restrict__ vt) {
    const int z = blockIdx.z;
    const float* X = (z == 0) ? q : (z == 1) ? k : v;
    const float* W = (z == 0) ? Wq : (z == 1) ? Wk : Wv;
    unsigned short* out = (z == 0) ? qh : (z == 1) ? kh : vt;
    const float wscale = (z == 0) ? (1.44269504f * 0.03125f) : 1.0f;

    const int lane = threadIdx.x & 63;
    const int wave = threadIdx.x >> 6;
    const int l16  = lane & 15;
    const int quad = lane >> 4;
    const int bh = blockIdx.y;
    const int b = bh >> 4, h = bh & 15;
    const int n0 = blockIdx.x * 64;
    const int tok = n0 + wave * 16 + l16;

    const float* xrow = X + ((size_t)(b * N_ + tok)) * E_ + h * 64;
    bf16x8 xf[2];
    xf[0] = cvt8s(xrow + quad * 8, 1.0f);
    xf[1] = cvt8s(xrow + 32 + quad * 8, 1.0f);

    const float* Wh = W + (size_t)h * 64 * 64;
    bf16x8 wf[4][2];
#pragma unroll
    for (int t4 = 0; t4 < 4; ++t4) {
        const float* wrow = Wh + (t4 * 16 + l16) * 64;
        wf[t4][0] = cvt8s(wrow + quad * 8, wscale);
        wf[t4][1] = cvt8s(wrow + 32 + quad * 8, wscale);
    }

    const int mk = (z == 0) ? mask[b * N_ + tok] : 1;

#pragma unroll
    for (int mi = 0; mi < 4; ++mi) {
        f32x4 a = {0.f, 0.f, 0.f, 0.f};
        a = MFMA(wf[mi][0], xf[0], a);   // D: row = dout, col = token (l16)
        a = MFMA(wf[mi][1], xf[1], a);
        if (z != 2) {
            i32x2 pk = {pack2bf(a.x, a.y), pack2bf(a.z, a.w)};
            if (!mk) pk = (i32x2){0, 0};
            *(i32x2*)(out + ((size_t)bh * N_ + tok) * 64 + mi * 16 + quad * 4) = pk;
        } else {
#pragma unroll
            for (int r = 0; r < 4; ++r) {
                int dout = mi * 16 + quad * 4 + r;
                out[((size_t)bh * 64 + dout) * N_ + tok] = (unsigned short)f2bf(a[r]);
            }
        }
    }
}

// ---------------------------------------------------------------------------
__global__ __launch_bounds__(256)
void cvt_wo_kernel(const float* __restrict__ wo, unsigned short* __restrict__ wob) {
    int idx = blockIdx.x * 256 + threadIdx.x;
    f32x4 v = *(const f32x4*)(wo + (size_t)idx * 4);
    i32x2 r = {pack2bf(v.x, v.y), pack2bf(v.z, v.w)};
    *(i32x2*)(wob + (size_t)idx * 4) = r;
}

// ---------------------------------------------------------------------------
// Flash attention, ZERO LDS staging, zero barriers.  LDS pipe was the
// saturated resource (frag reads 1.5K + staging 0.4K + bpermute 1.7K cyc
// per CU/iter at round 8); K/V frags now load DIRECTLY from global.  The
// XCD swizzle keeps each XCD's K/V working set (4 heads = 2 MB) inside its
// 4 MB L2, so the direct loads are L2 hits (~200cyc), hidden by:
//   - K frags for tile kt+1 prefetched into registers during iter kt
//   - V frags issued at iter top, consumed at iter end (after softmax)
// Shuffle-based P transform (C->B layout) kept.  No-max softmax; qh
// pre-scaled by log2e/32 and pre-masked at proj time.
// grid (16,32) = 512 blocks, 4 waves x 32 q-rows.
// ---------------------------------------------------------------------------
__global__ __launch_bounds__(256, 2)
void attn_kernel(const unsigned short* __restrict__ qh,
                 const unsigned short* __restrict__ kh,
                 const unsigned short* __restrict__ vt,
                 unsigned short* __restrict__ attnb) {
    const int tid  = threadIdx.x;
    const int lane = tid & 63;
    const int wave = tid >> 6;
    const int l16  = lane & 15;
    const int quad = lane >> 4;

    const int flat = blockIdx.y * gridDim.x + blockIdx.x;   // 0..511
    const int qblk = flat >> 5;
    const int rem  = flat & 31;
    const int bh   = ((rem & 7) << 2) | (rem >> 3);          // 4 heads per XCD
    const int b = bh >> 4, h = bh & 15;
    const int q0 = qblk * 128 + wave * 32;

    // per-lane base pointers
    const unsigned short* kp = kh + (size_t)bh * N_ * 64 + l16 * 64 + quad * 8;
    const unsigned short* vp = vt + (size_t)bh * 64 * N_ + (size_t)l16 * N_ + quad * 8;

    const int srcA = (((quad * 2) & 3) << 4) + l16;
    const int srcB = (((quad * 2 + 1) & 3) << 4) + l16;
    const bool hiSel = (quad >= 2);

    bf16x8 qf[2][2];
#pragma unroll
    for (int qi = 0; qi < 2; ++qi) {
        const unsigned short* qrow = qh + ((size_t)bh * N_ + q0 + qi * 16 + l16) * 64;
        qf[qi][0] = *(const bf16x8*)(qrow + quad * 8);
        qf[qi][1] = *(const bf16x8*)(qrow + 32 + quad * 8);
    }

    float lI[2] = {0.f, 0.f};
    f32x4 o[4][2];
#pragma unroll
    for (int mi = 0; mi < 4; ++mi)
#pragma unroll
        for (int qi = 0; qi < 2; ++qi) o[mi][qi] = (f32x4){0.f, 0.f, 0.f, 0.f};

    // K frags for tile 0
    bf16x8 ka[4][2];
#pragma unroll
    for (int t4 = 0; t4 < 4; ++t4) {
        ka[t4][0] = *(const bf16x8*)(kp + (size_t)(t4 * 16) * 64);
        ka[t4][1] = *(const bf16x8*)(kp + (size_t)(t4 * 16) * 64 + 32);
    }

    for (int kt = 0; kt < N_ / 64; ++kt) {
        // prefetch K frags for tile kt+1 (consumed next iter -> latency hidden)
        bf16x8 kan[4][2];
        if (kt + 1 < N_ / 64) {
            const unsigned short* kpn = kp + (size_t)(kt + 1) * 64 * 64;
#pragma unroll
            for (int t4 = 0; t4 < 4; ++t4) {
                kan[t4][0] = *(const bf16x8*)(kpn + (size_t)(t4 * 16) * 64);
                kan[t4][1] = *(const bf16x8*)(kpn + (size_t)(t4 * 16) * 64 + 32);
            }
        }

        // V frags for tile kt — issue now, consumed after softmax
        bf16x8 va[4][2];
#pragma unroll
        for (int mi = 0; mi < 4; ++mi) {
            const unsigned short* vrow = vp + (size_t)(mi * 16) * N_ + kt * 64;
            va[mi][0] = *(const bf16x8*)(vrow);
            va[mi][1] = *(const bf16x8*)(vrow + 32);
        }

        // QK^T for tile kt
        f32x4 s[2][4];
#pragma unroll
        for (int qi = 0; qi < 2; ++qi)
#pragma unroll
            for (int t4 = 0; t4 < 4; ++t4) {
                f32x4 z = {0.f, 0.f, 0.f, 0.f};
                z = MFMA(ka[t4][0], qf[qi][0], z);
                z = MFMA(ka[t4][1], qf[qi][1], z);
                s[qi][t4] = z;
            }

        // softmax + P transform + PV
#pragma unroll
        for (int qi = 0; qi < 2; ++qi) {
            float rsum = 0.f;
            int pk[4][2];
#pragma unroll
            for (int t4 = 0; t4 < 4; ++t4) {
                f32x4 p;
#pragma unroll
                for (int r = 0; r < 4; ++r) {
                    p[r] = __builtin_amdgcn_exp2f(s[qi][t4][r]);
                    rsum += p[r];
                }
                pk[t4][0] = pack2bf(p.x, p.y);
                pk[t4][1] = pack2bf(p.z, p.w);
            }
            rsum += __shfl_xor(rsum, 16);
            rsum += __shfl_xor(rsum, 32);
            lI[qi] += rsum;

            i32x4 w0, w1;
#pragma unroll
            for (int d = 0; d < 2; ++d) {
                int a0 = __shfl(pk[0][d], srcA), a1 = __shfl(pk[1][d], srcA);
                int b0 = __shfl(pk[0][d], srcB), b1 = __shfl(pk[1][d], srcB);
                w0[d]     = hiSel ? a1 : a0;
                w0[2 + d] = hiSel ? b1 : b0;
                int c0 = __shfl(pk[2][d], srcA), c1 = __shfl(pk[3][d], srcA);
                int e0 = __shfl(pk[2][d], srcB), e1 = __shfl(pk[3][d], srcB);
                w1[d]     = hiSel ? c1 : c0;
                w1[2 + d] = hiSel ? e1 : e0;
            }
            bf16x8 pb0 = __builtin_bit_cast(bf16x8, w0);
            bf16x8 pb1 = __builtin_bit_cast(bf16x8, w1);

#pragma unroll
            for (int mi = 0; mi < 4; ++mi) {
                o[mi][qi] = MFMA(va[mi][0], pb0, o[mi][qi]);
                o[mi][qi] = MFMA(va[mi][1], pb1, o[mi][qi]);
            }
        }

        // rotate prefetched K frags
#pragma unroll
        for (int t4 = 0; t4 < 4; ++t4) {
            ka[t4][0] = kan[t4][0];
            ka[t4][1] = kan[t4][1];
        }
    }

#pragma unroll
    for (int qi = 0; qi < 2; ++qi) {
        const float inv = 1.0f / lI[qi];
        const int qrow_idx = q0 + qi * 16 + l16;
#pragma unroll
        for (int mi = 0; mi < 4; ++mi) {
            f32x4 ov = o[mi][qi];
            i32x2 pkk = {pack2bf(ov.x * inv, ov.y * inv),
                         pack2bf(ov.z * inv, ov.w * inv)};
            int d0 = mi * 16 + quad * 4;
            *(i32x2*)(attnb + ((size_t)(b * N_ + qrow_idx)) * E_ + h * 64 + d0) = pkk;
        }
    }
}

// ---------------------------------------------------------------------------
// out = attnb(4096x1024 bf16) @ wob^T(1024x1024) -> fp32.  128x128 tile,
// BK=32, global_load_lds w16, dbuf LDS (chunk-linear), 512 thr = 8 waves
// (2m x 4n of 64x32), 1 chunk/thread/array per stage.  grid (32,8).
// ---------------------------------------------------------------------------
__global__ __launch_bounds__(512, 1)
void out_gemm_kernel(const unsigned short* __restrict__ A,
                     const unsigned short* __restrict__ Bw,
                     float* __restrict__ out) {
    __shared__ short As[2][128 * 32];   // 8 KB each
    __shared__ short Bs[2][128 * 32];

    const int tid  = threadIdx.x;
    const int lane = tid & 63;
    const int l16  = lane & 15;
    const int quad = lane >> 4;
    const int wave = tid >> 6;
    const int wm = wave & 1, wn = wave >> 1;
    const int m0 = blockIdx.x * 128;
    const int n0 = blockIdx.y * 128;

    const unsigned short* gA = A + (size_t)m0 * E_;
    const unsigned short* gB = Bw + (size_t)n0 * E_;

    f32x4 acc[4][2];
#pragma unroll
    for (int mt = 0; mt < 4; ++mt)
#pragma unroll
        for (int nt = 0; nt < 2; ++nt) acc[mt][nt] = (f32x4){0.f, 0.f, 0.f, 0.f};

    const int cc = tid >> 7, rr = tid & 127;
#define OG_STAGE(buf, k0)                                                        \
    {                                                                            \
        __builtin_amdgcn_global_load_lds(AS1(gA + (size_t)rr * E_ + (k0) + cc * 8), \
                                         AS3(&As[buf][tid * 8]), 16, 0, 0);      \
        __builtin_amdgcn_global_load_lds(AS1(gB + (size_t)rr * E_ + (k0) + cc * 8), \
                                         AS3(&Bs[buf][tid * 8]), 16, 0, 0);      \
    }

    OG_STAGE(0, 0)
    __syncthreads();

    for (int kt = 0; kt < E_ / 32; ++kt) {
        const int cur = kt & 1;
        if (kt + 1 < E_ / 32) OG_STAGE(cur ^ 1, (kt + 1) * 32)

        bf16x8 af[4], bf[2];
#pragma unroll
        for (int mt = 0; mt < 4; ++mt)
            af[mt] = *(const bf16x8*)(&As[cur][(quad * 128 + wm * 64 + mt * 16 + l16) * 8]);
#pragma unroll
        for (int nt = 0; nt < 2; ++nt)
            bf[nt] = *(const bf16x8*)(&Bs[cur][(quad * 128 + wn * 32 + nt * 16 + l16) * 8]);

#pragma unroll
        for (int mt = 0; mt < 4; ++mt)
#pragma unroll
            for (int nt = 0; nt < 2; ++nt)
                acc[mt][nt] = MFMA(af[mt], bf[nt], acc[mt][nt]);

        __syncthreads();
    }

#pragma unroll
    for (int mt = 0; mt < 4; ++mt)
#pragma unroll
        for (int nt = 0; nt < 2; ++nt)
#pragma unroll
            for (int r = 0; r < 4; ++r)
                out[(size_t)(m0 + wm * 64 + mt * 16 + quad * 4 + r) * E_ +
                    n0 + wn * 32 + nt * 16 + l16] = acc[mt][nt][r];
#undef OG_STAGE
}

// ---------------------------------------------------------------------------
extern "C" void kernel_launch(void* const* d_in, const int* in_sizes, int n_in,
                              void* d_out, int out_size, void* d_ws, size_t ws_size,
                              hipStream_t stream) {
    const float* q    = (const float*)d_in[0];
    const float* k    = (const float*)d_in[1];
    const float* v    = (const float*)d_in[2];
    const int*   mask = (const int*)d_in[3];
    const float* Wq   = (const float*)d_in[4];
    const float* Wk   = (const float*)d_in[5];
    const float* Wv   = (const float*)d_in[6];
    const float* Wo   = (const float*)d_in[7];
    float* out = (float*)d_out;

    char* ws = (char*)d_ws;
    unsigned short* qh    = (unsigned short*)(ws);
    unsigned short* kh    = (unsigned short*)(ws + (size_t)8 * 1024 * 1024);
    unsigned short* vt    = (unsigned short*)(ws + (size_t)16 * 1024 * 1024);
    unsigned short* attnb = (unsigned short*)(ws + (size_t)24 * 1024 * 1024);
    // wob aliases qh's region: cvt_wo runs AFTER attn is done reading qh.
    unsigned short* wob   = (unsigned short*)(ws);

    dim3 blk(256);
    proj_kernel<<<dim3(N_ / 64, BH_, 3), blk, 0, stream>>>(q, k, v, Wq, Wk, Wv, mask,
                                                           qh, kh, vt);
    attn_kernel<<<dim3(16, 32), blk, 0, stream>>>(qh, kh, vt, attnb);
    cvt_wo_kernel<<<dim3(E_ * E_ / 1024), blk, 0, stream>>>(Wo, wob);
    out_gemm_kernel<<<dim3(32, 8), dim3(512), 0, stream>>>(attnb, wob, out);
}

// Round 11
// 199.909 us; speedup vs baseline: 1.3756x; 1.3756x over previous
//
#include <hip/hip_runtime.h>
#include <hip/hip_bf16.h>

#define B_ 2
#define N_ 2048
#define E_ 1024
#define H_ 16
#define D_ 64
#define BH_ (B_ * H_)

typedef __attribute__((ext_vector_type(4))) float f32x4;
typedef __attribute__((ext_vector_type(8))) short bf16x8;
typedef __attribute__((ext_vector_type(4))) short s16x4;
typedef __attribute__((ext_vector_type(4))) int i32x4;
typedef __attribute__((ext_vector_type(2))) int i32x2;
typedef __attribute__((ext_vector_type(4))) _Float16 f16x4;

#define MFMA(a, b, c) __builtin_amdgcn_mfma_f32_16x16x32_bf16(a, b, c, 0, 0, 0)
#define MFMA16(a, b, c) __builtin_amdgcn_mfma_f32_16x16x16f16(a, b, c, 0, 0, 0)

#define AS1(p) ((const __attribute__((address_space(1))) unsigned int*)(p))
#define AS3(p) ((__attribute__((address_space(3))) unsigned int*)(p))

static __device__ __forceinline__ unsigned short f2bf(float f) {
    unsigned int u = __builtin_bit_cast(unsigned int, f);
    u += 0x7fff + ((u >> 16) & 1);   // RNE; inputs are finite
    return (unsigned short)(u >> 16);
}
static __device__ __forceinline__ int pack2bf(float lo, float hi) {
    __hip_bfloat162 t = __float22bfloat162_rn(float2{lo, hi});
    int r;
    __builtin_memcpy(&r, &t, 4);
    return r;
}
static __device__ __forceinline__ bf16x8 cvt8s(const float* __restrict__ p, float sc) {
    f32x4 a = *(const f32x4*)p;
    f32x4 b = *(const f32x4*)(p + 4);
    i32x4 r = {pack2bf(a.x * sc, a.y * sc), pack2bf(a.z * sc, a.w * sc),
               pack2bf(b.x * sc, b.y * sc), pack2bf(b.z * sc, b.w * sc)};
    return __builtin_bit_cast(bf16x8, r);
}
// 4x f32 -> f16x4 via two v_cvt_pkrtz_f16_f32 (RTZ; P in [0,1], fine)
static __device__ __forceinline__ f16x4 pack4f16(f32x4 p) {
    auto lo = __builtin_amdgcn_cvt_pkrtz(p.x, p.y);   // __fp16 x2
    auto hi = __builtin_amdgcn_cvt_pkrtz(p.z, p.w);
    f16x4 r;
    __builtin_memcpy(&r, &lo, 4);
    __builtin_memcpy(((char*)&r) + 4, &hi, 4);
    return r;
}

// ---------------------------------------------------------------------------
// Fused projections: z=0 -> qh = (q@Wq^T)*log2e/32, masked rows zeroed,
// layout [bh][n][d] bf16; z=1 -> kh [bh][n][d] bf16;
// z=2 -> vt [bh][d][n] in F16 (PV runs f16 16x16x16 MFMA).
// grid (N/64, BH, 3), block 256.
// ---------------------------------------------------------------------------
__global__ __launch_bounds__(256, 4)
void proj_kernel(const float* __restrict__ q, const float* __restrict__ k,
                 const float* __restrict__ v,
                 const float* __restrict__ Wq, const float* __restrict__ Wk,
                 const float* __restrict__ Wv,
                 const int* __restrict__ mask,
                 unsigned short* __restrict__ qh, unsigned short* __restrict__ kh,
                 unsigned short* __restrict__ vt) {
    const int z = blockIdx.z;
    const float* X = (z == 0) ? q : (z == 1) ? k : v;
    const float* W = (z == 0) ? Wq : (z == 1) ? Wk : Wv;
    unsigned short* out = (z == 0) ? qh : (z == 1) ? kh : vt;
    const float wscale = (z == 0) ? (1.44269504f * 0.03125f) : 1.0f;

    const int lane = threadIdx.x & 63;
    const int wave = threadIdx.x >> 6;
    const int l16  = lane & 15;
    const int quad = lane >> 4;
    const int bh = blockIdx.y;
    const int b = bh >> 4, h = bh & 15;
    const int n0 = blockIdx.x * 64;
    const int tok = n0 + wave * 16 + l16;

    const float* xrow = X + ((size_t)(b * N_ + tok)) * E_ + h * 64;
    bf16x8 xf[2];
    xf[0] = cvt8s(xrow + quad * 8, 1.0f);
    xf[1] = cvt8s(xrow + 32 + quad * 8, 1.0f);

    const float* Wh = W + (size_t)h * 64 * 64;
    bf16x8 wf[4][2];
#pragma unroll
    for (int t4 = 0; t4 < 4; ++t4) {
        const float* wrow = Wh + (t4 * 16 + l16) * 64;
        wf[t4][0] = cvt8s(wrow + quad * 8, wscale);
        wf[t4][1] = cvt8s(wrow + 32 + quad * 8, wscale);
    }

    const int mk = (z == 0) ? mask[b * N_ + tok] : 1;

#pragma unroll
    for (int mi = 0; mi < 4; ++mi) {
        f32x4 a = {0.f, 0.f, 0.f, 0.f};
        a = MFMA(wf[mi][0], xf[0], a);   // D: row = dout, col = token (l16)
        a = MFMA(wf[mi][1], xf[1], a);
        if (z != 2) {
            i32x2 pk = {pack2bf(a.x, a.y), pack2bf(a.z, a.w)};
            if (!mk) pk = (i32x2){0, 0};
            *(i32x2*)(out + ((size_t)bh * N_ + tok) * 64 + mi * 16 + quad * 4) = pk;
        } else {
#pragma unroll
            for (int r = 0; r < 4; ++r) {
                int dout = mi * 16 + quad * 4 + r;
                _Float16 hv = (_Float16)a[r];
                unsigned short us;
                __builtin_memcpy(&us, &hv, 2);
                out[((size_t)bh * 64 + dout) * N_ + tok] = us;
            }
        }
    }
}

// ---------------------------------------------------------------------------
__global__ __launch_bounds__(256)
void cvt_wo_kernel(const float* __restrict__ wo, unsigned short* __restrict__ wob) {
    int idx = blockIdx.x * 256 + threadIdx.x;
    f32x4 v = *(const f32x4*)(wo + (size_t)idx * 4);
    i32x2 r = {pack2bf(v.x, v.y), pack2bf(v.z, v.w)};
    *(i32x2*)(wob + (size_t)idx * 4) = r;
}

// ---------------------------------------------------------------------------
// Flash attention.  Key trick: PV uses v_mfma_f32_16x16x16_f16, whose
// B-operand layout (B[k=quad*4+j][n=l16]) EQUALS the QK C/D layout
// (row=key=quad*4+r, col=q=l16) -> P needs NO cross-lane transform at all
// (round 8 spent 32 ds_bpermute/iter on it).  V stored/staged as f16.
// K dbuf [64][72] (conflict-free b128 r/w); V triple-buffer [64][76]
// (stride 76: b64 frag reads AND b128 staging writes hit all 32 banks
// exactly once).  PV(t-1) pipelined behind QK(t) (round 8 structure).
// No-max softmax; qh pre-scaled+masked at proj.  One barrier/iter.
// grid (16,32)=512 blocks (XCD swizzle: 4 heads/XCD -> K/V L2-resident).
// ---------------------------------------------------------------------------
__global__ __launch_bounds__(256, 2)
void attn_kernel(const unsigned short* __restrict__ qh,
                 const unsigned short* __restrict__ kh,
                 const unsigned short* __restrict__ vt,
                 unsigned short* __restrict__ attnb) {
    __shared__ short Kb[2][64 * 72];   // 18 KB
    __shared__ short Vb[3][64 * 76];   // 28.5 KB

    const int tid  = threadIdx.x;
    const int lane = tid & 63;
    const int wave = tid >> 6;
    const int l16  = lane & 15;
    const int quad = lane >> 4;

    const int flat = blockIdx.y * gridDim.x + blockIdx.x;   // 0..511
    const int qblk = flat >> 5;
    const int rem  = flat & 31;
    const int bh   = ((rem & 7) << 2) | (rem >> 3);          // 4 heads per XCD
    const int b = bh >> 4, h = bh & 15;
    const int q0 = qblk * 128 + wave * 32;

    const unsigned short* kbase = kh + (size_t)bh * N_ * 64;
    const unsigned short* vbase = vt + (size_t)bh * 64 * N_;

    const int c0i = tid;
    const int c1i = tid + 256;
    const int k0o = (c0i >> 3) * 72 + (c0i & 7) * 8;
    const int k1o = (c1i >> 3) * 72 + (c1i & 7) * 8;
    const int v0o = (c0i >> 3) * 76 + (c0i & 7) * 8;
    const int v1o = (c1i >> 3) * 76 + (c1i & 7) * 8;

    short* kcur  = &Kb[0][0];
    short* knext = &Kb[1][0];
    short* vprev = &Vb[2][0];
    short* vcur  = &Vb[0][0];
    short* vnext = &Vb[1][0];

    bf16x8 qf[2][2];
#pragma unroll
    for (int qi = 0; qi < 2; ++qi) {
        const unsigned short* qrow = qh + ((size_t)bh * N_ + q0 + qi * 16 + l16) * 64;
        qf[qi][0] = *(const bf16x8*)(qrow + quad * 8);
        qf[qi][1] = *(const bf16x8*)(qrow + 32 + quad * 8);
    }

    f32x4 psum[2] = {{0.f, 0.f, 0.f, 0.f}, {0.f, 0.f, 0.f, 0.f}};
    f32x4 o[4][2];
#pragma unroll
    for (int mi = 0; mi < 4; ++mi)
#pragma unroll
        for (int qi = 0; qi < 2; ++qi) o[mi][qi] = (f32x4){0.f, 0.f, 0.f, 0.f};

    f16x4 pf[2][4];   // saved P frags (16x16x16 B-operand) from previous tile

    // stage tile 0
    bf16x8 gK0, gK1, gV0, gV1;
    gK0 = *(const bf16x8*)(kbase + c0i * 8);
    gK1 = *(const bf16x8*)(kbase + c1i * 8);
    gV0 = *(const bf16x8*)(vbase + (size_t)(c0i >> 3) * N_ + (c0i & 7) * 8);
    gV1 = *(const bf16x8*)(vbase + (size_t)(c1i >> 3) * N_ + (c1i & 7) * 8);
    *(bf16x8*)(kcur + k0o) = gK0;
    *(bf16x8*)(kcur + k1o) = gK1;
    *(bf16x8*)(vcur + v0o) = gV0;
    *(bf16x8*)(vcur + v1o) = gV1;
    __syncthreads();

    for (int kt = 0; kt < N_ / 64; ++kt) {
        // global prefetch of tile kt+1
        if (kt + 1 < N_ / 64) {
            const int k0n = (kt + 1) * 64;
            gK0 = *(const bf16x8*)(kbase + (size_t)k0n * 64 + c0i * 8);
            gK1 = *(const bf16x8*)(kbase + (size_t)k0n * 64 + c1i * 8);
            gV0 = *(const bf16x8*)(vbase + (size_t)(c0i >> 3) * N_ + k0n + (c0i & 7) * 8);
            gV1 = *(const bf16x8*)(vbase + (size_t)(c1i >> 3) * N_ + k0n + (c1i & 7) * 8);
        }

        // K frags + QK^T for tile kt
        bf16x8 ka[4][2];
#pragma unroll
        for (int t4 = 0; t4 < 4; ++t4) {
            ka[t4][0] = *(const bf16x8*)(kcur + (t4 * 16 + l16) * 72 + quad * 8);
            ka[t4][1] = *(const bf16x8*)(kcur + (t4 * 16 + l16) * 72 + 32 + quad * 8);
        }
        f32x4 s[2][4];
#pragma unroll
        for (int qi = 0; qi < 2; ++qi)
#pragma unroll
            for (int t4 = 0; t4 < 4; ++t4) {
                f32x4 z = {0.f, 0.f, 0.f, 0.f};
                z = MFMA(ka[t4][0], qf[qi][0], z);
                z = MFMA(ka[t4][1], qf[qi][1], z);
                s[qi][t4] = z;
            }

        // PV for tile kt-1 (independent of this iter's chain)
        if (kt > 0) {
#pragma unroll
            for (int mi = 0; mi < 4; ++mi) {
#pragma unroll
                for (int t4 = 0; t4 < 4; ++t4) {
                    f16x4 va = *(const f16x4*)(vprev + (mi * 16 + l16) * 76 +
                                               t4 * 16 + quad * 4);
#pragma unroll
                    for (int qi = 0; qi < 2; ++qi)
                        o[mi][qi] = MFMA16(va, pf[qi][t4], o[mi][qi]);
                }
            }
        }

        // softmax tile kt -> pf (NO transform: C-layout == 16x16x16 B-layout)
#pragma unroll
        for (int qi = 0; qi < 2; ++qi) {
#pragma unroll
            for (int t4 = 0; t4 < 4; ++t4) {
                f32x4 p;
#pragma unroll
                for (int r = 0; r < 4; ++r) p[r] = __builtin_amdgcn_exp2f(s[qi][t4][r]);
                psum[qi] += p;
                pf[qi][t4] = pack4f16(p);
            }
        }

        // stage tile kt+1, one barrier
        if (kt + 1 < N_ / 64) {
            *(bf16x8*)(knext + k0o) = gK0;
            *(bf16x8*)(knext + k1o) = gK1;
            *(bf16x8*)(vnext + v0o) = gV0;
            *(bf16x8*)(vnext + v1o) = gV1;
            __syncthreads();
        }

        // rotate buffers
        short* t = kcur; kcur = knext; knext = t;
        short* tv = vprev; vprev = vcur; vcur = vnext; vnext = tv;
    }

    // drain: PV for the last tile
#pragma unroll
    for (int mi = 0; mi < 4; ++mi) {
#pragma unroll
        for (int t4 = 0; t4 < 4; ++t4) {
            f16x4 va = *(const f16x4*)(vprev + (mi * 16 + l16) * 76 +
                                       t4 * 16 + quad * 4);
#pragma unroll
            for (int qi = 0; qi < 2; ++qi)
                o[mi][qi] = MFMA16(va, pf[qi][t4], o[mi][qi]);
        }
    }

    // row-sum reduction (once per kernel, not per iter)
#pragma unroll
    for (int qi = 0; qi < 2; ++qi) {
        float rs = psum[qi].x + psum[qi].y + psum[qi].z + psum[qi].w;
        rs += __shfl_xor(rs, 16);
        rs += __shfl_xor(rs, 32);
        const float inv = 1.0f / rs;
        const int qrow_idx = q0 + qi * 16 + l16;
#pragma unroll
        for (int mi = 0; mi < 4; ++mi) {
            f32x4 ov = o[mi][qi];
            i32x2 pkk = {pack2bf(ov.x * inv, ov.y * inv),
                         pack2bf(ov.z * inv, ov.w * inv)};
            int d0 = mi * 16 + quad * 4;
            *(i32x2*)(attnb + ((size_t)(b * N_ + qrow_idx)) * E_ + h * 64 + d0) = pkk;
        }
    }
}

// ---------------------------------------------------------------------------
// out = attnb(4096x1024 bf16) @ wob^T(1024x1024) -> fp32.  128x128 tile,
// BK=32, global_load_lds w16, dbuf LDS (chunk-linear), 512 thr = 8 waves
// (2m x 4n of 64x32), 1 chunk/thread/array per stage.  grid (32,8).
// ---------------------------------------------------------------------------
__global__ __launch_bounds__(512, 1)
void out_gemm_kernel(const unsigned short* __restrict__ A,
                     const unsigned short* __restrict__ Bw,
                     float* __restrict__ out) {
    __shared__ short As[2][128 * 32];   // 8 KB each
    __shared__ short Bs[2][128 * 32];

    const int tid  = threadIdx.x;
    const int lane = tid & 63;
    const int l16  = lane & 15;
    const int quad = lane >> 4;
    const int wave = tid >> 6;
    const int wm = wave & 1, wn = wave >> 1;
    const int m0 = blockIdx.x * 128;
    const int n0 = blockIdx.y * 128;

    const unsigned short* gA = A + (size_t)m0 * E_;
    const unsigned short* gB = Bw + (size_t)n0 * E_;

    f32x4 acc[4][2];
#pragma unroll
    for (int mt = 0; mt < 4; ++mt)
#pragma unroll
        for (int nt = 0; nt < 2; ++nt) acc[mt][nt] = (f32x4){0.f, 0.f, 0.f, 0.f};

    const int cc = tid >> 7, rr = tid & 127;
#define OG_STAGE(buf, k0)                                                        \
    {                                                                            \
        __builtin_amdgcn_global_load_lds(AS1(gA + (size_t)rr * E_ + (k0) + cc * 8), \
                                         AS3(&As[buf][tid * 8]), 16, 0, 0);      \
        __builtin_amdgcn_global_load_lds(AS1(gB + (size_t)rr * E_ + (k0) + cc * 8), \
                                         AS3(&Bs[buf][tid * 8]), 16, 0, 0);      \
    }

    OG_STAGE(0, 0)
    __syncthreads();

    for (int kt = 0; kt < E_ / 32; ++kt) {
        const int cur = kt & 1;
        if (kt + 1 < E_ / 32) OG_STAGE(cur ^ 1, (kt + 1) * 32)

        bf16x8 af[4], bf[2];
#pragma unroll
        for (int mt = 0; mt < 4; ++mt)
            af[mt] = *(const bf16x8*)(&As[cur][(quad * 128 + wm * 64 + mt * 16 + l16) * 8]);
#pragma unroll
        for (int nt = 0; nt < 2; ++nt)
            bf[nt] = *(const bf16x8*)(&Bs[cur][(quad * 128 + wn * 32 + nt * 16 + l16) * 8]);

#pragma unroll
        for (int mt = 0; mt < 4; ++mt)
#pragma unroll
            for (int nt = 0; nt < 2; ++nt)
                acc[mt][nt] = MFMA(af[mt], bf[nt], acc[mt][nt]);

        __syncthreads();
    }

#pragma unroll
    for (int mt = 0; mt < 4; ++mt)
#pragma unroll
        for (int nt = 0; nt < 2; ++nt)
#pragma unroll
            for (int r = 0; r < 4; ++r)
                out[(size_t)(m0 + wm * 64 + mt * 16 + quad * 4 + r) * E_ +
                    n0 + wn * 32 + nt * 16 + l16] = acc[mt][nt][r];
#undef OG_STAGE
}

// ---------------------------------------------------------------------------
extern "C" void kernel_launch(void* const* d_in, const int* in_sizes, int n_in,
                              void* d_out, int out_size, void* d_ws, size_t ws_size,
                              hipStream_t stream) {
    const float* q    = (const float*)d_in[0];
    const float* k    = (const float*)d_in[1];
    const float* v    = (const float*)d_in[2];
    const int*   mask = (const int*)d_in[3];
    const float* Wq   = (const float*)d_in[4];
    const float* Wk   = (const float*)d_in[5];
    const float* Wv   = (const float*)d_in[6];
    const float* Wo   = (const float*)d_in[7];
    float* out = (float*)d_out;

    char* ws = (char*)d_ws;
    unsigned short* qh    = (unsigned short*)(ws);
    unsigned short* kh    = (unsigned short*)(ws + (size_t)8 * 1024 * 1024);
    unsigned short* vt    = (unsigned short*)(ws + (size_t)16 * 1024 * 1024);
    unsigned short* attnb = (unsigned short*)(ws + (size_t)24 * 1024 * 1024);
    // wob aliases qh's region: cvt_wo runs AFTER attn is done reading qh.
    unsigned short* wob   = (unsigned short*)(ws);

    dim3 blk(256);
    proj_kernel<<<dim3(N_ / 64, BH_, 3), blk, 0, stream>>>(q, k, v, Wq, Wk, Wv, mask,
                                                           qh, kh, vt);
    attn_kernel<<<dim3(16, 32), blk, 0, stream>>>(qh, kh, vt, attnb);
    cvt_wo_kernel<<<dim3(E_ * E_ / 1024), blk, 0, stream>>>(Wo, wob);
    out_gemm_kernel<<<dim3(32, 8), dim3(512), 0, stream>>>(attnb, wob, out);
}